// Round 12
// baseline (201.778 us; speedup 1.0000x reference)
//
#include <hip/hip_runtime.h>
#include <hip/hip_bf16.h>
#include <stdint.h>

#define S_LEN   2048
#define D_MODEL 1024
#define NH      16
#define DH      64
#define BATCH   2
#define TOKENS  (BATCH * S_LEN)   // 4096

typedef __bf16 bf16;
typedef __bf16 bf16x8 __attribute__((ext_vector_type(8)));
typedef __bf16 b16x4  __attribute__((ext_vector_type(4)));
typedef float  f32x4  __attribute__((ext_vector_type(4)));

__device__ __forceinline__ void async_lds16(const void* g, void* l) {
  __builtin_amdgcn_global_load_lds((__attribute__((address_space(1))) void*)g,
                                   (__attribute__((address_space(3))) void*)l,
                                   16, 0, 0);
}

// ---------------------------------------------------------------------------
// fp32 -> bf16 converts. conv2: x and wqkv in one dispatch.
// ---------------------------------------------------------------------------
__device__ __forceinline__ void conv8(const float* src, bf16* dst, int i) {
  const f32x4 a = *(const f32x4*)(src + (size_t)i * 8);
  const f32x4 b = *(const f32x4*)(src + (size_t)i * 8 + 4);
  bf16x8 o;
#pragma unroll
  for (int j = 0; j < 4; j++) { o[j] = (bf16)a[j]; o[j + 4] = (bf16)b[j]; }
  *(bf16x8*)(dst + (size_t)i * 8) = o;
}

__global__ __launch_bounds__(256) void convert2_kernel(
    const float* __restrict__ s0, bf16* __restrict__ d0, int n0_,
    const float* __restrict__ s1, bf16* __restrict__ d1, int n1_) {
  const int i = blockIdx.x * 256 + threadIdx.x;
  if (i < n0_) conv8(s0, d0, i);
  else if (i - n0_ < n1_) conv8(s1, d1, i - n0_);
}

__global__ __launch_bounds__(256) void convert_kernel(
    const float* __restrict__ src, bf16* __restrict__ dst, int n8) {
  const int i = blockIdx.x * 256 + threadIdx.x;
  if (i < n8) conv8(src, dst, i);
}

// ---------------------------------------------------------------------------
// GEMM core (m97-style): C = A * B^T, bf16, async global->LDS, 128x128, BK=32.
// ---------------------------------------------------------------------------
#define BM 128
#define BN 128
#define BK 32

#define GEMM_CORE(APTR, BPTR, KDIM)                                              \
  __shared__ __align__(16) bf16 As[BM * BK];                                     \
  __shared__ __align__(16) bf16 Bs[BN * BK];                                     \
  const int tid  = threadIdx.x;                                                  \
  const int wave = tid >> 6, lane = tid & 63;                                    \
  const int quad = lane >> 4, l16 = lane & 15;                                   \
  const int m0 = blockIdx.y * BM;                                                \
  const int n0 = blockIdx.x * BN;                                                \
  const int wm = (wave >> 1) * 64, wn = (wave & 1) * 64;                         \
  f32x4 acc[4][4] = {};                                                          \
  const int c0 = tid, c1 = tid + 256;                                            \
  for (int k0 = 0; k0 < (KDIM); k0 += BK) {                                      \
    async_lds16((APTR) + (size_t)(m0 + (c0 >> 2)) * (KDIM) + k0 + (c0 & 3) * 8,  \
                As + c0 * 8);                                                    \
    async_lds16((APTR) + (size_t)(m0 + (c1 >> 2)) * (KDIM) + k0 + (c1 & 3) * 8,  \
                As + c1 * 8);                                                    \
    async_lds16((BPTR) + (size_t)(n0 + (c0 >> 2)) * (KDIM) + k0 + (c0 & 3) * 8,  \
                Bs + c0 * 8);                                                    \
    async_lds16((BPTR) + (size_t)(n0 + (c1 >> 2)) * (KDIM) + k0 + (c1 & 3) * 8,  \
                Bs + c1 * 8);                                                    \
    __syncthreads();                                                             \
    bf16x8 af[4], bfr[4];                                                        \
    _Pragma("unroll") for (int i = 0; i < 4; i++)                                \
        af[i] = *(const bf16x8*)(As + (wm + i * 16 + l16) * BK + quad * 8);      \
    _Pragma("unroll") for (int j = 0; j < 4; j++)                                \
        bfr[j] = *(const bf16x8*)(Bs + (wn + j * 16 + l16) * BK + quad * 8);     \
    _Pragma("unroll") for (int i = 0; i < 4; i++)                                \
      _Pragma("unroll") for (int j = 0; j < 4; j++)                              \
        acc[i][j] = __builtin_amdgcn_mfma_f32_16x16x32_bf16(af[i], bfr[j],       \
                                                            acc[i][j], 0, 0, 0); \
    __syncthreads();                                                             \
  }

// GEMM 1: qkv = xb @ Wqkvb^T -> Q (b,h,s,d, x1/8), K (b,h,s,d), VT (b,h,d,s).
__global__ __launch_bounds__(256) void gemm_qkv_kernel(
    const bf16* __restrict__ X, const bf16* __restrict__ W,
    bf16* __restrict__ Qo, bf16* __restrict__ Ko, bf16* __restrict__ VTo) {
  GEMM_CORE(X, W, D_MODEL)
  const int t = n0 >> 10;  // 0=q 1=k 2=v (uniform per block)
#pragma unroll
  for (int i = 0; i < 4; i++) {
    const int rowb = m0 + wm + i * 16 + quad * 4;   // multiple of 4
    const int b = rowb >> 11, s0 = rowb & 2047;
#pragma unroll
    for (int j = 0; j < 4; j++) {
      const int col = n0 + wn + j * 16 + l16;
      const int h = (col >> 6) & 15, d = col & 63;
      if (t == 2) {
        b16x4 v4;
#pragma unroll
        for (int r = 0; r < 4; r++) v4[r] = (bf16)acc[i][j][r];
        *(b16x4*)(VTo + ((size_t)(b * NH + h) * DH + d) * S_LEN + s0) = v4;
      } else {
#pragma unroll
        for (int r = 0; r < 4; r++) {
          const float v = acc[i][j][r];
          if (t == 0)
            Qo[((size_t)(b * NH + h) * S_LEN + s0 + r) * DH + d] = (bf16)(v * 0.125f);
          else
            Ko[((size_t)(b * NH + h) * S_LEN + s0 + r) * DH + d] = (bf16)v;
        }
      }
    }
  }
}

// GEMM 2: out = AO @ Woutb^T -> fp32. 64x128 tile (grid 512 = 2 blocks/CU;
// the 128x128 version ran at 1 block/CU and was the occupancy-worst kernel).
__global__ __launch_bounds__(256) void gemm_out_kernel(
    const bf16* __restrict__ A, const bf16* __restrict__ W,
    float* __restrict__ Out) {
  __shared__ __align__(16) bf16 As[64 * BK];
  __shared__ __align__(16) bf16 Bs[128 * BK];
  const int tid  = threadIdx.x;
  const int wave = tid >> 6, lane = tid & 63;
  const int quad = lane >> 4, l16 = lane & 15;
  const int m0 = blockIdx.y * 64;
  const int n0 = blockIdx.x * 128;
  const int wm = (wave >> 1) * 32, wn = (wave & 1) * 64;
  f32x4 acc[2][4] = {};
  const int c0 = tid, c1 = tid + 256;   // A: 256 chunks; B: 512 chunks
  for (int k0 = 0; k0 < D_MODEL; k0 += BK) {
    async_lds16(A + (size_t)(m0 + (c0 >> 2)) * D_MODEL + k0 + (c0 & 3) * 8,
                As + c0 * 8);
    async_lds16(W + (size_t)(n0 + (c0 >> 2)) * D_MODEL + k0 + (c0 & 3) * 8,
                Bs + c0 * 8);
    async_lds16(W + (size_t)(n0 + (c1 >> 2)) * D_MODEL + k0 + (c1 & 3) * 8,
                Bs + c1 * 8);
    __syncthreads();
    bf16x8 af[2], bfr[4];
#pragma unroll
    for (int i = 0; i < 2; i++)
      af[i] = *(const bf16x8*)(As + (wm + i * 16 + l16) * BK + quad * 8);
#pragma unroll
    for (int j = 0; j < 4; j++)
      bfr[j] = *(const bf16x8*)(Bs + (wn + j * 16 + l16) * BK + quad * 8);
#pragma unroll
    for (int i = 0; i < 2; i++)
#pragma unroll
      for (int j = 0; j < 4; j++)
        acc[i][j] = __builtin_amdgcn_mfma_f32_16x16x32_bf16(af[i], bfr[j],
                                                            acc[i][j], 0, 0, 0);
    __syncthreads();
  }
#pragma unroll
  for (int i = 0; i < 2; i++) {
    const int rowb = m0 + wm + i * 16 + quad * 4;
#pragma unroll
    for (int j = 0; j < 4; j++) {
      const int col = n0 + wn + j * 16 + l16;
#pragma unroll
      for (int r = 0; r < 4; r++)
        Out[(size_t)(rowb + r) * D_MODEL + col] = acc[i][j][r];
    }
  }
}

// ---------------------------------------------------------------------------
// Flash attention v6: 256 threads (4 waves) x 16 q-rows = 64 q/block,
// grid 1024 -> 5 blocks/CU (LDS 27.6KB), ~20 waves/CU. Transposed scores;
// P^T per-wave LDS (b64 writes, b128 reads); PV full-rate K=32 MFMA.
// ---------------------------------------------------------------------------
#define AKS 72
#define AVS 72
#define PTS 72

__global__ __launch_bounds__(256) void attn_kernel(
    const bf16* __restrict__ Q, const bf16* __restrict__ K,
    const bf16* __restrict__ VT, bf16* __restrict__ AO) {
  __shared__ __align__(16) bf16 Ks[64 * AKS];
  __shared__ __align__(16) bf16 Vs[64 * AVS];
  __shared__ __align__(16) bf16 PT[4 * 16 * PTS];

  const int tid  = threadIdx.x;
  const int wave = tid >> 6, lane = tid & 63;
  const int quad = lane >> 4, l16 = lane & 15;
  const int qb = blockIdx.x & 31;   // 2048/64 q-tiles
  const int bh = blockIdx.x >> 5;   // 0..31
  const bf16* qp = Q  + (size_t)bh * S_LEN * DH;
  const bf16* kp = K  + (size_t)bh * S_LEN * DH;
  const bf16* vp = VT + (size_t)bh * DH * S_LEN;
  const int qr0 = qb * 64 + wave * 16;   // 16 q-rows per wave

  const bf16x8 aq0 = *(const bf16x8*)(qp + (size_t)(qr0 + l16) * DH + quad * 8);
  const bf16x8 aq1 = *(const bf16x8*)(qp + (size_t)(qr0 + l16) * DH + 32 + quad * 8);

  f32x4 oT[4] = {};                    // row=d=quad*4+r, col=q=l16
  float lsum = 0.f;
  bf16* PTw = PT + wave * (16 * PTS);  // per-wave private

  // staging: 256 threads x 2 chunks of 8 = 64x64 tile each for K and V
  const int rc0 = tid >> 3, rc1 = rc0 + 32, kc = (tid & 7) * 8;

  // prefetch kb=0
  bf16x8 kv0 = *(const bf16x8*)(kp + (size_t)rc0 * DH + kc);
  bf16x8 kv1 = *(const bf16x8*)(kp + (size_t)rc1 * DH + kc);
  bf16x8 vv0 = *(const bf16x8*)(vp + (size_t)rc0 * S_LEN + kc);
  bf16x8 vv1 = *(const bf16x8*)(vp + (size_t)rc1 * S_LEN + kc);

  for (int kb = 0; kb < S_LEN / 64; kb++) {
    __syncthreads();   // prior reads of Ks/Vs done
    *(bf16x8*)(Ks + rc0 * AKS + kc) = kv0;
    *(bf16x8*)(Ks + rc1 * AKS + kc) = kv1;
    *(bf16x8*)(Vs + rc0 * AVS + kc) = vv0;
    *(bf16x8*)(Vs + rc1 * AVS + kc) = vv1;
    __syncthreads();   // tiles visible

    const int kn = (kb + 1 < S_LEN / 64) ? kb + 1 : kb;
    kv0 = *(const bf16x8*)(kp + (size_t)(kn * 64 + rc0) * DH + kc);
    kv1 = *(const bf16x8*)(kp + (size_t)(kn * 64 + rc1) * DH + kc);
    vv0 = *(const bf16x8*)(vp + (size_t)rc0 * S_LEN + kn * 64 + kc);
    vv1 = *(const bf16x8*)(vp + (size_t)rc1 * S_LEN + kn * 64 + kc);

    // S^T = K Q^T per 16-key subtile; exp; pack 4 keys -> one b64 P^T write
#pragma unroll
    for (int t = 0; t < 4; t++) {
      const bf16x8 ak0 = *(const bf16x8*)(Ks + (t * 16 + l16) * AKS + quad * 8);
      const bf16x8 ak1 = *(const bf16x8*)(Ks + (t * 16 + l16) * AKS + 32 + quad * 8);
      f32x4 st = {};
      st = __builtin_amdgcn_mfma_f32_16x16x32_bf16(ak0, aq0, st, 0, 0, 0);
      st = __builtin_amdgcn_mfma_f32_16x16x32_bf16(ak1, aq1, st, 0, 0, 0);
      b16x4 pb;
      float ls = 0.f;
#pragma unroll
      for (int r = 0; r < 4; r++) {
        const float e = __expf(st[r]);
        ls += e;
        pb[r] = (bf16)e;
      }
      lsum += ls;
      *(b16x4*)(PTw + l16 * PTS + t * 16 + quad * 4) = pb;
    }

    // PV at K=32: O^T[d][q] += V^T[d][key] * P^T[key][q]
#pragma unroll
    for (int c = 0; c < 2; c++) {
      const bf16x8 pf = *(const bf16x8*)(PTw + l16 * PTS + c * 32 + quad * 8);
#pragma unroll
      for (int nt = 0; nt < 4; nt++) {
        const bf16x8 av =
            *(const bf16x8*)(Vs + (nt * 16 + l16) * AVS + c * 32 + quad * 8);
        oT[nt] = __builtin_amdgcn_mfma_f32_16x16x32_bf16(av, pf, oT[nt], 0, 0, 0);
      }
    }
  }

  // denominator: sum across the 4 quads (same q=l16)
  lsum += __shfl_xor(lsum, 16);
  lsum += __shfl_xor(lsum, 32);
  const float inv = 1.0f / (lsum + 1e-6f);

  const int b = bh >> 4, h = bh & 15;
  const int srow = qr0 + l16;
  const size_t base = (size_t)(b * S_LEN + srow) * D_MODEL + h * DH;
#pragma unroll
  for (int nt = 0; nt < 4; nt++) {
    b16x4 o4;
#pragma unroll
    for (int r = 0; r < 4; r++) o4[r] = (bf16)(oT[nt][r] * inv);
    *(b16x4*)(AO + base + nt * 16 + quad * 4) = o4;   // d=nt*16+quad*4+r
  }
}

extern "C" void kernel_launch(void* const* d_in, const int* in_sizes, int n_in,
                              void* d_out, int out_size, void* d_ws, size_t ws_size,
                              hipStream_t stream) {
  const float* x    = (const float*)d_in[0];
  const float* wqkv = (const float*)d_in[1];
  const float* wout = (const float*)d_in[2];
  float* out = (float*)d_out;

  // ws (32 MB): [Q 8MB][K 8MB][VT 8MB][xb 8MB -> AO after gemm_qkv]
  bf16* Q  = (bf16*)d_ws;
  bf16* K  = Q  + (size_t)TOKENS * D_MODEL;
  bf16* VT = K  + (size_t)TOKENS * D_MODEL;
  bf16* xb = VT + (size_t)TOKENS * D_MODEL;
  bf16* AO = xb;                       // xb dead after gemm_qkv
  bf16* wqkvb = (bf16*)d_out;          // d_out dead until gemm_out
  bf16* woutb = Q;                     // Q dead after attn

  const int nx8 = TOKENS * D_MODEL / 8;             // 524288
  const int nw8 = 3 * D_MODEL * D_MODEL / 8;        // 393216
  convert2_kernel<<<dim3((nx8 + nw8 + 255) / 256), dim3(256), 0, stream>>>(
      x, xb, nx8, wqkv, wqkvb, nw8);

  gemm_qkv_kernel<<<dim3(3 * D_MODEL / BN, TOKENS / BM), dim3(256), 0, stream>>>(
      xb, wqkvb, Q, K, VT);

  attn_kernel<<<dim3(BATCH * NH * (S_LEN / 64)), dim3(256), 0, stream>>>(Q, K, VT, AO);

  convert_kernel<<<dim3(D_MODEL * D_MODEL / (256 * 8)), dim3(256), 0, stream>>>(
      wout, woutb, D_MODEL * D_MODEL / 8);

  gemm_out_kernel<<<dim3(D_MODEL / 128, TOKENS / 64), dim3(256), 0, stream>>>(
      AO, woutb, out);
}